// Round 5
// baseline (206.719 us; speedup 1.0000x reference)
//
#include <hip/hip_runtime.h>

// YOLOv1 loss on MI355X — round 5.
// R4: main 68us @ 1.23 TB/s, VALU 4.9%, occ 25% => latency-bound.
//   Cause 1: cls/bbox loads gated behind lr-load + branch (serial latency).
//   Cause 2: 784 blocks = 3 blocks/CU, ~12 waves/CU.
// Fix: branchless (all 16 loads/thread independent, issued up front; masked
//   accumulate) + 3136 blocks x 1 cell/thread for ~full occupancy.

constexpr int NCELL  = 4096 * 14 * 14;   // 802816
constexpr int TPB    = 256;
constexpr int BLOCKS = NCELL / TPB;      // 3136, exact

constexpr float INV_BS  = 1.0f / 4096.0f;
constexpr float L_COORD = 5.0f;
constexpr float L_NOOBJ = 0.5f;

__device__ __forceinline__ float iou_corners(float4 t, float4 p) {
    float thx = 0.5f * t.z * t.z;
    float thy = 0.5f * t.w * t.w;
    float t_l = t.x - thx, t_t = t.y - thy;
    float t_r = t.x + thx, t_b = t.y + thy;
    float phx = 0.5f * p.z * p.z;
    float phy = 0.5f * p.w * p.w;
    float p_l = p.x - phx, p_t = p.y - phy;
    float p_r = p.x + phx, p_b = p.y + phy;
    float ltx = fmaxf(t_l, p_l), lty = fmaxf(t_t, p_t);
    float rbx = fminf(t_r, p_r), rby = fminf(t_b, p_b);
    float wx = fmaxf(rbx - ltx, 0.0f), wy = fmaxf(rby - lty, 0.0f);
    float inter = wx * wy;
    float a1 = (t_r - t_l) * (t_b - t_t);
    float a2 = (p_r - p_l) * (p_b - p_t);
    return inter / (a1 + a2 - inter);
}

__global__ __launch_bounds__(TPB) void yolo_loss_main(
    const float* __restrict__ pred_cls,    // [NCELL][20]
    const float* __restrict__ pred_resp,   // [NCELL][2]
    const float* __restrict__ pred_bb,     // [NCELL][8]
    const float* __restrict__ label_cls,   // [NCELL][20]
    const float* __restrict__ label_resp,  // [NCELL][2]
    const float* __restrict__ label_bb,    // [NCELL][8]
    float* __restrict__ ws)                // [BLOCKS][8] partials
{
    const int cell = blockIdx.x * TPB + threadIdx.x;

    // ---- issue ALL loads up front, fully independent (no branch gating) ----
    const float2 lr = *reinterpret_cast<const float2*>(label_resp + (size_t)cell * 2);
    const float2 pr = *reinterpret_cast<const float2*>(pred_resp  + (size_t)cell * 2);

    const float4* pc = reinterpret_cast<const float4*>(pred_cls  + (size_t)cell * 20);
    const float4* lc = reinterpret_cast<const float4*>(label_cls + (size_t)cell * 20);
    float4 a0 = pc[0], a1 = pc[1], a2 = pc[2], a3 = pc[3], a4 = pc[4];
    float4 b0 = lc[0], b1 = lc[1], b2 = lc[2], b3 = lc[3], b4 = lc[4];

    const float4* pbp = reinterpret_cast<const float4*>(pred_bb  + (size_t)cell * 8);
    const float4* tbp = reinterpret_cast<const float4*>(label_bb + (size_t)cell * 8);
    float4 pb0 = pbp[0], pb1 = pbp[1];
    float4 tb0 = tbp[0], tb1 = tbp[1];

    // ---- masks ----
    const float obj  = (lr.x > 0.0f) ? 1.0f : 0.0f;
    const float nob  = 1.0f - obj;

    // ---- noobj response loss ----
    float d0 = pr.x - lr.x, d1 = pr.y - lr.y;
    float nobj = nob * (d0 * d0 + d1 * d1);

    // ---- classification loss ----
    float c = 0.0f;
    {
        float dx, dy, dz, dw;
        dx = a0.x-b0.x; dy = a0.y-b0.y; dz = a0.z-b0.z; dw = a0.w-b0.w; c += dx*dx+dy*dy+dz*dz+dw*dw;
        dx = a1.x-b1.x; dy = a1.y-b1.y; dz = a1.z-b1.z; dw = a1.w-b1.w; c += dx*dx+dy*dy+dz*dz+dw*dw;
        dx = a2.x-b2.x; dy = a2.y-b2.y; dz = a2.z-b2.z; dw = a2.w-b2.w; c += dx*dx+dy*dy+dz*dz+dw*dw;
        dx = a3.x-b3.x; dy = a3.y-b3.y; dz = a3.z-b3.z; dw = a3.w-b3.w; c += dx*dx+dy*dy+dz*dz+dw*dw;
        dx = a4.x-b4.x; dy = a4.y-b4.y; dz = a4.z-b4.z; dw = a4.w-b4.w; c += dx*dx+dy*dy+dz*dz+dw*dw;
    }
    float cls = obj * c;

    // ---- bbox / iou terms ----
    float iou0 = iou_corners(tb0, pb0);
    float iou1 = iou_corners(tb1, pb1);
    bool best1 = iou1 > iou0;                 // jnp.argmax: first max wins
    float max_iou = fmaxf(iou0, iou1);

    float4 bp = best1 ? pb1 : pb0;
    float4 bt = best1 ? tb1 : tb0;
    float ex = bp.x - bt.x, ey = bp.y - bt.y, ez = bp.z - bt.z, ew = bp.w - bt.w;
    float coord = obj * (ex * ex + ey * ey + ez * ez + ew * ew);

    float pr_best = best1 ? pr.y : pr.x;
    float lr_best = best1 ? lr.y : lr.x;
    float dpo = pr_best - max_iou;
    float dio = max_iou - lr_best;
    float pobj = obj * dpo * dpo;
    float iouL = obj * dio * dio;

    // ---- wave (64-lane) reduction ----
    #pragma unroll
    for (int off = 32; off > 0; off >>= 1) {
        coord += __shfl_down(coord, off);
        cls   += __shfl_down(cls,   off);
        pobj  += __shfl_down(pobj,  off);
        nobj  += __shfl_down(nobj,  off);
        iouL  += __shfl_down(iouL,  off);
    }

    // ---- block reduction (4 waves) ----
    __shared__ float part[4][5];
    int wave = threadIdx.x >> 6;
    int lane = threadIdx.x & 63;
    if (lane == 0) {
        part[wave][0] = coord;
        part[wave][1] = cls;
        part[wave][2] = pobj;
        part[wave][3] = nobj;
        part[wave][4] = iouL;
    }
    __syncthreads();
    if (threadIdx.x == 0) {
        float* w = ws + (size_t)blockIdx.x * 8;
        w[0] = part[0][0] + part[1][0] + part[2][0] + part[3][0];
        w[1] = part[0][1] + part[1][1] + part[2][1] + part[3][1];
        w[2] = part[0][2] + part[1][2] + part[2][2] + part[3][2];
        w[3] = part[0][3] + part[1][3] + part[2][3] + part[3][3];
        w[4] = part[0][4] + part[1][4] + part[2][4] + part[3][4];
    }
}

__global__ __launch_bounds__(TPB) void yolo_loss_finish(
    const float* __restrict__ ws,   // [BLOCKS][8]
    float* __restrict__ out)        // [5]
{
    float s0 = 0.0f, s1 = 0.0f, s2 = 0.0f, s3 = 0.0f, s4 = 0.0f;
    for (int b = threadIdx.x; b < BLOCKS; b += TPB) {
        const float* w = ws + (size_t)b * 8;
        s0 += w[0]; s1 += w[1]; s2 += w[2]; s3 += w[3]; s4 += w[4];
    }
    #pragma unroll
    for (int off = 32; off > 0; off >>= 1) {
        s0 += __shfl_down(s0, off);
        s1 += __shfl_down(s1, off);
        s2 += __shfl_down(s2, off);
        s3 += __shfl_down(s3, off);
        s4 += __shfl_down(s4, off);
    }
    __shared__ float part[4][5];
    int wave = threadIdx.x >> 6;
    int lane = threadIdx.x & 63;
    if (lane == 0) {
        part[wave][0] = s0; part[wave][1] = s1; part[wave][2] = s2;
        part[wave][3] = s3; part[wave][4] = s4;
    }
    __syncthreads();
    if (threadIdx.x == 0) {
        float t0 = part[0][0] + part[1][0] + part[2][0] + part[3][0];
        float t1 = part[0][1] + part[1][1] + part[2][1] + part[3][1];
        float t2 = part[0][2] + part[1][2] + part[2][2] + part[3][2];
        float t3 = part[0][3] + part[1][3] + part[2][3] + part[3][3];
        float t4 = part[0][4] + part[1][4] + part[2][4] + part[3][4];
        out[0] = L_COORD * INV_BS * t0;
        out[1] = INV_BS * t1;
        out[2] = INV_BS * t2;
        out[3] = L_NOOBJ * INV_BS * t3;
        out[4] = INV_BS * t4;
    }
}

extern "C" void kernel_launch(void* const* d_in, const int* in_sizes, int n_in,
                              void* d_out, int out_size, void* d_ws, size_t ws_size,
                              hipStream_t stream) {
    const float* pred_cls   = (const float*)d_in[0];
    const float* pred_resp  = (const float*)d_in[1];
    const float* pred_bb    = (const float*)d_in[2];
    const float* label_cls  = (const float*)d_in[3];
    const float* label_resp = (const float*)d_in[4];
    const float* label_bb   = (const float*)d_in[5];
    float* ws  = (float*)d_ws;          // BLOCKS*8 floats = 98 KB
    float* out = (float*)d_out;

    yolo_loss_main<<<BLOCKS, TPB, 0, stream>>>(
        pred_cls, pred_resp, pred_bb, label_cls, label_resp, label_bb, ws);
    yolo_loss_finish<<<1, TPB, 0, stream>>>(ws, out);
}

// Round 6
// 202.965 us; speedup vs baseline: 1.0185x; 1.0185x over previous
//
#include <hip/hip_runtime.h>

// YOLOv1 loss on MI355X — round 6.
// R5: 75us @ 1.3 TB/s, VALU 5%, occ 58% (occupancy doubled vs R4, no gain)
//   => NOT latency-bound; vmem request-rate bound. Per-cell-per-thread loads
//   are stride-80B/32B across lanes: ~472 cache-line requests per wave vs
//   ~120 ideal (4x TA/L1 overload).
// Fix: flat-index decomposition — every load dense across lanes.
//   cls:  flat over NCELL*5 float4s (each float4 within one cell; obj mask is
//         a ~1-line/wave gather from label_resp[2*(i4/5)]).
//   bbox: flat over NCELL*2 boxes; thread = one box (float4 pb/tb + scalar
//         pr/lr, all dense); partner IoU via __shfl_xor(iou,1); tie -> box0
//         (b0 uses >=, b1 uses >). label_response tiled => lr>0 is obj.

constexpr int NCELL    = 4096 * 14 * 14;   // 802816 = 2^14 * 49
constexpr int TPB      = 256;
constexpr int BLOCKS   = NCELL / TPB;      // 3136
constexpr int NTHREADS = NCELL;            // grid size = 802816 threads
constexpr int CLS_IT   = 5;                // NCELL*5 float4s / NTHREADS
constexpr int BOX_IT   = 2;                // NCELL*2 boxes  / NTHREADS

constexpr float INV_BS  = 1.0f / 4096.0f;
constexpr float L_COORD = 5.0f;
constexpr float L_NOOBJ = 0.5f;

__device__ __forceinline__ float iou_corners(float4 t, float4 p) {
    float thx = 0.5f * t.z * t.z;
    float thy = 0.5f * t.w * t.w;
    float t_l = t.x - thx, t_t = t.y - thy;
    float t_r = t.x + thx, t_b = t.y + thy;
    float phx = 0.5f * p.z * p.z;
    float phy = 0.5f * p.w * p.w;
    float p_l = p.x - phx, p_t = p.y - phy;
    float p_r = p.x + phx, p_b = p.y + phy;
    float ltx = fmaxf(t_l, p_l), lty = fmaxf(t_t, p_t);
    float rbx = fminf(t_r, p_r), rby = fminf(t_b, p_b);
    float wx = fmaxf(rbx - ltx, 0.0f), wy = fmaxf(rby - lty, 0.0f);
    float inter = wx * wy;
    float a1 = (t_r - t_l) * (t_b - t_t);
    float a2 = (p_r - p_l) * (p_b - p_t);
    return inter / (a1 + a2 - inter);
}

__global__ __launch_bounds__(TPB) void yolo_loss_main(
    const float* __restrict__ pred_cls,    // [NCELL*20]
    const float* __restrict__ pred_resp,   // [NCELL*2]
    const float* __restrict__ pred_bb,     // [NCELL*8]
    const float* __restrict__ label_cls,   // [NCELL*20]
    const float* __restrict__ label_resp,  // [NCELL*2]
    const float* __restrict__ label_bb,    // [NCELL*8]
    float* __restrict__ ws)                // [BLOCKS][8] partials
{
    const int tid = blockIdx.x * TPB + threadIdx.x;

    float coord = 0.0f, cls = 0.0f, pobj = 0.0f, nobj = 0.0f, iouL = 0.0f;

    // ---- Phase A: classification loss, fully dense float4 streams ----
    const float4* pc4 = reinterpret_cast<const float4*>(pred_cls);
    const float4* lc4 = reinterpret_cast<const float4*>(label_cls);
    #pragma unroll
    for (int j = 0; j < CLS_IT; ++j) {
        unsigned i4 = (unsigned)(j * NTHREADS + tid);
        float4 a = pc4[i4];
        float4 b = lc4[i4];
        unsigned cell = i4 / 5u;                       // magic-mul div
        float o = (label_resp[(size_t)cell * 2] > 0.0f) ? 1.0f : 0.0f;
        float dx = a.x - b.x, dy = a.y - b.y, dz = a.z - b.z, dw = a.w - b.w;
        cls += o * (dx * dx + dy * dy + dz * dz + dw * dw);
    }

    // ---- Phase B: boxes flat (thread = one box), all loads dense ----
    const float4* pb4 = reinterpret_cast<const float4*>(pred_bb);
    const float4* tb4 = reinterpret_cast<const float4*>(label_bb);
    #pragma unroll
    for (int j = 0; j < BOX_IT; ++j) {
        int bi = j * NTHREADS + tid;                   // box index, parity == lane parity
        float4 p = pb4[bi];
        float4 t = tb4[bi];
        float prv = pred_resp[bi];
        float lrv = label_resp[bi];                    // tiled obj bit: valid per-box

        float iou   = iou_corners(t, p);
        float iou_o = __shfl_xor(iou, 1);              // partner box of same cell
        bool  is_b1 = (bi & 1);
        bool  win   = is_b1 ? (iou > iou_o) : (iou >= iou_o);  // argmax: first max wins
        float mx    = fmaxf(iou, iou_o);

        float obj = (lrv > 0.0f) ? 1.0f : 0.0f;
        float dr  = prv - lrv;
        nobj += (1.0f - obj) * dr * dr;                // summed over both boxes ✔

        float wm = win ? obj : 0.0f;
        float ex = p.x - t.x, ey = p.y - t.y, ez = p.z - t.z, ew = p.w - t.w;
        coord += wm * (ex * ex + ey * ey + ez * ez + ew * ew);
        float dpo = prv - mx;
        float dio = mx - lrv;
        pobj += wm * dpo * dpo;
        iouL += wm * dio * dio;
    }

    // ---- wave (64-lane) reduction ----
    #pragma unroll
    for (int off = 32; off > 0; off >>= 1) {
        coord += __shfl_down(coord, off);
        cls   += __shfl_down(cls,   off);
        pobj  += __shfl_down(pobj,  off);
        nobj  += __shfl_down(nobj,  off);
        iouL  += __shfl_down(iouL,  off);
    }

    // ---- block reduction (4 waves) ----
    __shared__ float part[4][5];
    int wave = threadIdx.x >> 6;
    int lane = threadIdx.x & 63;
    if (lane == 0) {
        part[wave][0] = coord;
        part[wave][1] = cls;
        part[wave][2] = pobj;
        part[wave][3] = nobj;
        part[wave][4] = iouL;
    }
    __syncthreads();
    if (threadIdx.x == 0) {
        float* w = ws + (size_t)blockIdx.x * 8;
        w[0] = part[0][0] + part[1][0] + part[2][0] + part[3][0];
        w[1] = part[0][1] + part[1][1] + part[2][1] + part[3][1];
        w[2] = part[0][2] + part[1][2] + part[2][2] + part[3][2];
        w[3] = part[0][3] + part[1][3] + part[2][3] + part[3][3];
        w[4] = part[0][4] + part[1][4] + part[2][4] + part[3][4];
    }
}

__global__ __launch_bounds__(TPB) void yolo_loss_finish(
    const float* __restrict__ ws,   // [BLOCKS][8]
    float* __restrict__ out)        // [5]
{
    float s0 = 0.0f, s1 = 0.0f, s2 = 0.0f, s3 = 0.0f, s4 = 0.0f;
    for (int b = threadIdx.x; b < BLOCKS; b += TPB) {
        const float* w = ws + (size_t)b * 8;
        s0 += w[0]; s1 += w[1]; s2 += w[2]; s3 += w[3]; s4 += w[4];
    }
    #pragma unroll
    for (int off = 32; off > 0; off >>= 1) {
        s0 += __shfl_down(s0, off);
        s1 += __shfl_down(s1, off);
        s2 += __shfl_down(s2, off);
        s3 += __shfl_down(s3, off);
        s4 += __shfl_down(s4, off);
    }
    __shared__ float part[4][5];
    int wave = threadIdx.x >> 6;
    int lane = threadIdx.x & 63;
    if (lane == 0) {
        part[wave][0] = s0; part[wave][1] = s1; part[wave][2] = s2;
        part[wave][3] = s3; part[wave][4] = s4;
    }
    __syncthreads();
    if (threadIdx.x == 0) {
        float t0 = part[0][0] + part[1][0] + part[2][0] + part[3][0];
        float t1 = part[0][1] + part[1][1] + part[2][1] + part[3][1];
        float t2 = part[0][2] + part[1][2] + part[2][2] + part[3][2];
        float t3 = part[0][3] + part[1][3] + part[2][3] + part[3][3];
        float t4 = part[0][4] + part[1][4] + part[2][4] + part[3][4];
        out[0] = L_COORD * INV_BS * t0;
        out[1] = INV_BS * t1;
        out[2] = INV_BS * t2;
        out[3] = L_NOOBJ * INV_BS * t3;
        out[4] = INV_BS * t4;
    }
}

extern "C" void kernel_launch(void* const* d_in, const int* in_sizes, int n_in,
                              void* d_out, int out_size, void* d_ws, size_t ws_size,
                              hipStream_t stream) {
    const float* pred_cls   = (const float*)d_in[0];
    const float* pred_resp  = (const float*)d_in[1];
    const float* pred_bb    = (const float*)d_in[2];
    const float* label_cls  = (const float*)d_in[3];
    const float* label_resp = (const float*)d_in[4];
    const float* label_bb   = (const float*)d_in[5];
    float* ws  = (float*)d_ws;          // BLOCKS*8 floats = 98 KB
    float* out = (float*)d_out;

    yolo_loss_main<<<BLOCKS, TPB, 0, stream>>>(
        pred_cls, pred_resp, pred_bb, label_cls, label_resp, label_bb, ws);
    yolo_loss_finish<<<1, TPB, 0, stream>>>(ws, out);
}

// Round 10
// 202.376 us; speedup vs baseline: 1.0215x; 1.0029x over previous
//
#include <hip/hip_runtime.h>

// YOLOv1 loss on MI355X — round 7 kernel (resubmit x3; R7/R8/R9 benches all
// failed on GPU acquisition, no counters since R6).
// R4/R5/R6 all ~70us with VALU<8%, HBM~17%, occupancy-insensitive, and time
// tracking FETCH_SIZE at ~1.3 TB/s effective. VGPR_Count was 32-36 every
// round => compiler consumes loads immediately (early waitcnt), ~2-4
// outstanding misses/wave. Little's law at ~375ns miss latency gives exactly
// the observed ~1.3-1.7 TB/s. Theory: MLP-bound.
// Fix: 1568 blocks, 10 cls float4-pairs + 4 boxes per thread, ALL loads
// issued before any consumption (named regs, full unroll), launch_bounds
// (256,1) to unpin the register allocator. Occupancy is spent deliberately.

constexpr int NCELL  = 4096 * 14 * 14;     // 802816
constexpr int TPB    = 256;
constexpr int BLOCKS = 1568;               // 401408 threads
constexpr int NT     = BLOCKS * TPB;       // 401408
constexpr int CLS_IT = 10;                 // NCELL*5 float4s / NT = 10 exact
constexpr int BOX_IT = 4;                  // NCELL*2 boxes  / NT = 4 exact

constexpr float INV_BS  = 1.0f / 4096.0f;
constexpr float L_COORD = 5.0f;
constexpr float L_NOOBJ = 0.5f;

__device__ __forceinline__ float iou_corners(float4 t, float4 p) {
    float thx = 0.5f * t.z * t.z;
    float thy = 0.5f * t.w * t.w;
    float t_l = t.x - thx, t_t = t.y - thy;
    float t_r = t.x + thx, t_b = t.y + thy;
    float phx = 0.5f * p.z * p.z;
    float phy = 0.5f * p.w * p.w;
    float p_l = p.x - phx, p_t = p.y - phy;
    float p_r = p.x + phx, p_b = p.y + phy;
    float ltx = fmaxf(t_l, p_l), lty = fmaxf(t_t, p_t);
    float rbx = fminf(t_r, p_r), rby = fminf(t_b, p_b);
    float wx = fmaxf(rbx - ltx, 0.0f), wy = fmaxf(rby - lty, 0.0f);
    float inter = wx * wy;
    float a1 = (t_r - t_l) * (t_b - t_t);
    float a2 = (p_r - p_l) * (p_b - p_t);
    return inter / (a1 + a2 - inter);
}

__global__ __launch_bounds__(TPB, 1) void yolo_loss_main(
    const float* __restrict__ pred_cls,    // [NCELL*20]
    const float* __restrict__ pred_resp,   // [NCELL*2]
    const float* __restrict__ pred_bb,     // [NCELL*8]
    const float* __restrict__ label_cls,   // [NCELL*20]
    const float* __restrict__ label_resp,  // [NCELL*2]
    const float* __restrict__ label_bb,    // [NCELL*8]
    float* __restrict__ ws)                // [BLOCKS][8] partials
{
    const int tid = blockIdx.x * TPB + threadIdx.x;

    // ================= Phase A: classification =================
    // Issue ALL 20 float4 loads + 10 mask loads before consuming anything.
    const float4* pc4 = reinterpret_cast<const float4*>(pred_cls);
    const float4* lc4 = reinterpret_cast<const float4*>(label_cls);

    float4 A[CLS_IT], B[CLS_IT];
    float  M[CLS_IT];
    #pragma unroll
    for (int j = 0; j < CLS_IT; ++j) {
        unsigned i4 = (unsigned)(j * NT + tid);
        A[j] = pc4[i4];
        B[j] = lc4[i4];
    }
    #pragma unroll
    for (int j = 0; j < CLS_IT; ++j) {
        unsigned i4 = (unsigned)(j * NT + tid);
        M[j] = label_resp[(size_t)(i4 / 5u) * 2];
    }

    float cls0 = 0.0f, cls1 = 0.0f;
    #pragma unroll
    for (int j = 0; j < CLS_IT; ++j) {
        float o = (M[j] > 0.0f) ? 1.0f : 0.0f;
        float dx = A[j].x - B[j].x, dy = A[j].y - B[j].y;
        float dz = A[j].z - B[j].z, dw = A[j].w - B[j].w;
        float s = dx * dx + dy * dy + dz * dz + dw * dw;
        if (j & 1) cls1 += o * s; else cls0 += o * s;
    }
    float cls = cls0 + cls1;

    // ================= Phase B: boxes (thread = one box) =================
    const float4* pb4 = reinterpret_cast<const float4*>(pred_bb);
    const float4* tb4 = reinterpret_cast<const float4*>(label_bb);

    float4 P[BOX_IT], T[BOX_IT];
    float  PR[BOX_IT], LR[BOX_IT];
    #pragma unroll
    for (int j = 0; j < BOX_IT; ++j) {
        int bi = j * NT + tid;
        P[j]  = pb4[bi];
        T[j]  = tb4[bi];
        PR[j] = pred_resp[bi];
        LR[j] = label_resp[bi];    // tiled obj bit: valid per-box
    }

    const bool is_b1 = (tid & 1);  // NT even => box parity == tid parity
    float coord = 0.0f, pobj = 0.0f, nobj = 0.0f, iouL = 0.0f;
    #pragma unroll
    for (int j = 0; j < BOX_IT; ++j) {
        float iou   = iou_corners(T[j], P[j]);
        float iou_o = __shfl_xor(iou, 1);                 // partner box, same cell
        bool  win   = is_b1 ? (iou > iou_o) : (iou >= iou_o);  // argmax: first max
        float mx    = fmaxf(iou, iou_o);

        float obj = (LR[j] > 0.0f) ? 1.0f : 0.0f;
        float dr  = PR[j] - LR[j];
        nobj += (1.0f - obj) * dr * dr;

        float wm = win ? obj : 0.0f;
        float ex = P[j].x - T[j].x, ey = P[j].y - T[j].y;
        float ez = P[j].z - T[j].z, ew = P[j].w - T[j].w;
        coord += wm * (ex * ex + ey * ey + ez * ez + ew * ew);
        float dpo = PR[j] - mx;
        float dio = mx - LR[j];
        pobj += wm * dpo * dpo;
        iouL += wm * dio * dio;
    }

    // ---- wave (64-lane) reduction ----
    #pragma unroll
    for (int off = 32; off > 0; off >>= 1) {
        coord += __shfl_down(coord, off);
        cls   += __shfl_down(cls,   off);
        pobj  += __shfl_down(pobj,  off);
        nobj  += __shfl_down(nobj,  off);
        iouL  += __shfl_down(iouL,  off);
    }

    // ---- block reduction (4 waves) ----
    __shared__ float part[4][5];
    int wave = threadIdx.x >> 6;
    int lane = threadIdx.x & 63;
    if (lane == 0) {
        part[wave][0] = coord;
        part[wave][1] = cls;
        part[wave][2] = pobj;
        part[wave][3] = nobj;
        part[wave][4] = iouL;
    }
    __syncthreads();
    if (threadIdx.x == 0) {
        float* w = ws + (size_t)blockIdx.x * 8;
        w[0] = part[0][0] + part[1][0] + part[2][0] + part[3][0];
        w[1] = part[0][1] + part[1][1] + part[2][1] + part[3][1];
        w[2] = part[0][2] + part[1][2] + part[2][2] + part[3][2];
        w[3] = part[0][3] + part[1][3] + part[2][3] + part[3][3];
        w[4] = part[0][4] + part[1][4] + part[2][4] + part[3][4];
    }
}

__global__ __launch_bounds__(TPB) void yolo_loss_finish(
    const float* __restrict__ ws,   // [BLOCKS][8]
    float* __restrict__ out)        // [5]
{
    float s0 = 0.0f, s1 = 0.0f, s2 = 0.0f, s3 = 0.0f, s4 = 0.0f;
    for (int b = threadIdx.x; b < BLOCKS; b += TPB) {
        const float* w = ws + (size_t)b * 8;
        s0 += w[0]; s1 += w[1]; s2 += w[2]; s3 += w[3]; s4 += w[4];
    }
    #pragma unroll
    for (int off = 32; off > 0; off >>= 1) {
        s0 += __shfl_down(s0, off);
        s1 += __shfl_down(s1, off);
        s2 += __shfl_down(s2, off);
        s3 += __shfl_down(s3, off);
        s4 += __shfl_down(s4, off);
    }
    __shared__ float part[4][5];
    int wave = threadIdx.x >> 6;
    int lane = threadIdx.x & 63;
    if (lane == 0) {
        part[wave][0] = s0; part[wave][1] = s1; part[wave][2] = s2;
        part[wave][3] = s3; part[wave][4] = s4;
    }
    __syncthreads();
    if (threadIdx.x == 0) {
        float t0 = part[0][0] + part[1][0] + part[2][0] + part[3][0];
        float t1 = part[0][1] + part[1][1] + part[2][1] + part[3][1];
        float t2 = part[0][2] + part[1][2] + part[2][2] + part[3][2];
        float t3 = part[0][3] + part[1][3] + part[2][3] + part[3][3];
        float t4 = part[0][4] + part[1][4] + part[2][4] + part[3][4];
        out[0] = L_COORD * INV_BS * t0;
        out[1] = INV_BS * t1;
        out[2] = INV_BS * t2;
        out[3] = L_NOOBJ * INV_BS * t3;
        out[4] = INV_BS * t4;
    }
}

extern "C" void kernel_launch(void* const* d_in, const int* in_sizes, int n_in,
                              void* d_out, int out_size, void* d_ws, size_t ws_size,
                              hipStream_t stream) {
    const float* pred_cls   = (const float*)d_in[0];
    const float* pred_resp  = (const float*)d_in[1];
    const float* pred_bb    = (const float*)d_in[2];
    const float* label_cls  = (const float*)d_in[3];
    const float* label_resp = (const float*)d_in[4];
    const float* label_bb   = (const float*)d_in[5];
    float* ws  = (float*)d_ws;          // BLOCKS*8 floats = 50 KB
    float* out = (float*)d_out;

    yolo_loss_main<<<BLOCKS, TPB, 0, stream>>>(
        pred_cls, pred_resp, pred_bb, label_cls, label_resp, label_bb, ws);
    yolo_loss_finish<<<1, TPB, 0, stream>>>(ws, out);
}

// Round 11
// 197.915 us; speedup vs baseline: 1.0445x; 1.0225x over previous
//
#include <hip/hip_runtime.h>

// YOLOv1 loss on MI355X — round 11: byte-minimal, branchless-predicated.
// History: R1 216us (atomic contention) -> R4 68us (branchy, 81MB fetch) ->
// R5/R6/R10 73-75us (branchless/dense/MLP-batched, 95-98MB fetch) with
// occupancy 25-63%, VGPR 36-64, coalesced or not ALL null. Only bytes ever
// moved the needle (81MB->68us vs 98MB->73us). Suspected external floor:
// harness restore traffic (~192MB d2d ~= 73us at 5.3TB/s) sharing the memory
// system; 1.35 (ours) + 5.3 (restore) ~= 6.3 TB/s ceiling.
// R11 lever: address-select predication (base = obj ? cell : 0) — noobj
// lanes collapse onto cell 0's L1-hot lines, saving ~50% of cls (80B/cell)
// and bbox (64B/cell) line traffic with NO divergent branches, so loads
// still batch for MLP. If this nulls too (>=68us) => platform floor =>
// ROOFLINE.

constexpr int NCELL  = 4096 * 14 * 14;     // 802816
constexpr int TPB    = 256;
constexpr int CPT    = 2;                  // cells per thread
constexpr int BLOCKS = NCELL / (TPB * CPT);// 1568
constexpr int NT     = BLOCKS * TPB;       // 401408

constexpr float INV_BS  = 1.0f / 4096.0f;
constexpr float L_COORD = 5.0f;
constexpr float L_NOOBJ = 0.5f;

__device__ __forceinline__ float iou_corners(float4 t, float4 p) {
    float thx = 0.5f * t.z * t.z;
    float thy = 0.5f * t.w * t.w;
    float t_l = t.x - thx, t_t = t.y - thy;
    float t_r = t.x + thx, t_b = t.y + thy;
    float phx = 0.5f * p.z * p.z;
    float phy = 0.5f * p.w * p.w;
    float p_l = p.x - phx, p_t = p.y - phy;
    float p_r = p.x + phx, p_b = p.y + phy;
    float ltx = fmaxf(t_l, p_l), lty = fmaxf(t_t, p_t);
    float rbx = fminf(t_r, p_r), rby = fminf(t_b, p_b);
    float wx = fmaxf(rbx - ltx, 0.0f), wy = fmaxf(rby - lty, 0.0f);
    float inter = wx * wy;
    float a1 = (t_r - t_l) * (t_b - t_t);
    float a2 = (p_r - p_l) * (p_b - p_t);
    return inter / (a1 + a2 - inter);
}

__global__ __launch_bounds__(TPB, 1) void yolo_loss_main(
    const float* __restrict__ pred_cls,    // [NCELL*20]
    const float* __restrict__ pred_resp,   // [NCELL*2]
    const float* __restrict__ pred_bb,     // [NCELL*8]
    const float* __restrict__ label_cls,   // [NCELL*20]
    const float* __restrict__ label_resp,  // [NCELL*2]
    const float* __restrict__ label_bb,    // [NCELL*8]
    float* __restrict__ ws)                // [BLOCKS][8] partials
{
    const int tid   = blockIdx.x * TPB + threadIdx.x;
    const int cellA = tid;                 // two cells per thread
    const int cellB = tid + NT;

    const float4* pc4 = reinterpret_cast<const float4*>(pred_cls);
    const float4* lc4 = reinterpret_cast<const float4*>(label_cls);
    const float4* pb4 = reinterpret_cast<const float4*>(pred_bb);
    const float4* tb4 = reinterpret_cast<const float4*>(label_bb);

    // ---- response loads (always needed), both cells, independent ----
    float2 lrA = *reinterpret_cast<const float2*>(label_resp + (size_t)cellA * 2);
    float2 prA = *reinterpret_cast<const float2*>(pred_resp  + (size_t)cellA * 2);
    float2 lrB = *reinterpret_cast<const float2*>(label_resp + (size_t)cellB * 2);
    float2 prB = *reinterpret_cast<const float2*>(pred_resp  + (size_t)cellB * 2);

    const float objA = (lrA.x > 0.0f) ? 1.0f : 0.0f;
    const float objB = (lrB.x > 0.0f) ? 1.0f : 0.0f;

    // Address-select predication: noobj lanes collapse to cell 0 (L1-hot).
    const size_t baA = (lrA.x > 0.0f) ? (size_t)cellA : 0;
    const size_t baB = (lrB.x > 0.0f) ? (size_t)cellB : 0;

    // ---- batch-issue all predicated loads for BOTH cells ----
    float4 A0 = pc4[baA * 5 + 0], A1 = pc4[baA * 5 + 1], A2 = pc4[baA * 5 + 2],
           A3 = pc4[baA * 5 + 3], A4 = pc4[baA * 5 + 4];
    float4 La0 = lc4[baA * 5 + 0], La1 = lc4[baA * 5 + 1], La2 = lc4[baA * 5 + 2],
           La3 = lc4[baA * 5 + 3], La4 = lc4[baA * 5 + 4];
    float4 pbA0 = pb4[baA * 2 + 0], pbA1 = pb4[baA * 2 + 1];
    float4 tbA0 = tb4[baA * 2 + 0], tbA1 = tb4[baA * 2 + 1];

    float4 B0 = pc4[baB * 5 + 0], B1 = pc4[baB * 5 + 1], B2 = pc4[baB * 5 + 2],
           B3 = pc4[baB * 5 + 3], B4 = pc4[baB * 5 + 4];
    float4 Lb0 = lc4[baB * 5 + 0], Lb1 = lc4[baB * 5 + 1], Lb2 = lc4[baB * 5 + 2],
           Lb3 = lc4[baB * 5 + 3], Lb4 = lc4[baB * 5 + 4];
    float4 pbB0 = pb4[baB * 2 + 0], pbB1 = pb4[baB * 2 + 1];
    float4 tbB0 = tb4[baB * 2 + 0], tbB1 = tb4[baB * 2 + 1];

    float coord = 0.0f, cls = 0.0f, pobj = 0.0f, nobj = 0.0f, iouL = 0.0f;

    // ================= cell A =================
    {
        float d0 = prA.x - lrA.x, d1 = prA.y - lrA.y;
        nobj += (1.0f - objA) * (d0 * d0 + d1 * d1);

        float c = 0.0f, dx, dy, dz, dw;
        dx = A0.x-La0.x; dy = A0.y-La0.y; dz = A0.z-La0.z; dw = A0.w-La0.w; c += dx*dx+dy*dy+dz*dz+dw*dw;
        dx = A1.x-La1.x; dy = A1.y-La1.y; dz = A1.z-La1.z; dw = A1.w-La1.w; c += dx*dx+dy*dy+dz*dz+dw*dw;
        dx = A2.x-La2.x; dy = A2.y-La2.y; dz = A2.z-La2.z; dw = A2.w-La2.w; c += dx*dx+dy*dy+dz*dz+dw*dw;
        dx = A3.x-La3.x; dy = A3.y-La3.y; dz = A3.z-La3.z; dw = A3.w-La3.w; c += dx*dx+dy*dy+dz*dz+dw*dw;
        dx = A4.x-La4.x; dy = A4.y-La4.y; dz = A4.z-La4.z; dw = A4.w-La4.w; c += dx*dx+dy*dy+dz*dz+dw*dw;
        cls += objA * c;

        float iou0 = iou_corners(tbA0, pbA0);
        float iou1 = iou_corners(tbA1, pbA1);
        bool  best1 = iou1 > iou0;                 // argmax: first max wins
        float mx = fmaxf(iou0, iou1);

        float4 bp = best1 ? pbA1 : pbA0;
        float4 bt = best1 ? tbA1 : tbA0;
        float ex = bp.x - bt.x, ey = bp.y - bt.y, ez = bp.z - bt.z, ew = bp.w - bt.w;
        coord += objA * (ex * ex + ey * ey + ez * ez + ew * ew);

        float pr_b = best1 ? prA.y : prA.x;
        float lr_b = best1 ? lrA.y : lrA.x;
        float dpo = pr_b - mx, dio = mx - lr_b;
        pobj += objA * dpo * dpo;
        iouL += objA * dio * dio;
    }

    // ================= cell B =================
    {
        float d0 = prB.x - lrB.x, d1 = prB.y - lrB.y;
        nobj += (1.0f - objB) * (d0 * d0 + d1 * d1);

        float c = 0.0f, dx, dy, dz, dw;
        dx = B0.x-Lb0.x; dy = B0.y-Lb0.y; dz = B0.z-Lb0.z; dw = B0.w-Lb0.w; c += dx*dx+dy*dy+dz*dz+dw*dw;
        dx = B1.x-Lb1.x; dy = B1.y-Lb1.y; dz = B1.z-Lb1.z; dw = B1.w-Lb1.w; c += dx*dx+dy*dy+dz*dz+dw*dw;
        dx = B2.x-Lb2.x; dy = B2.y-Lb2.y; dz = B2.z-Lb2.z; dw = B2.w-Lb2.w; c += dx*dx+dy*dy+dz*dz+dw*dw;
        dx = B3.x-Lb3.x; dy = B3.y-Lb3.y; dz = B3.z-Lb3.z; dw = B3.w-Lb3.w; c += dx*dx+dy*dy+dz*dz+dw*dw;
        dx = B4.x-Lb4.x; dy = B4.y-Lb4.y; dz = B4.z-Lb4.z; dw = B4.w-Lb4.w; c += dx*dx+dy*dy+dz*dz+dw*dw;
        cls += objB * c;

        float iou0 = iou_corners(tbB0, pbB0);
        float iou1 = iou_corners(tbB1, pbB1);
        bool  best1 = iou1 > iou0;
        float mx = fmaxf(iou0, iou1);

        float4 bp = best1 ? pbB1 : pbB0;
        float4 bt = best1 ? tbB1 : tbB0;
        float ex = bp.x - bt.x, ey = bp.y - bt.y, ez = bp.z - bt.z, ew = bp.w - bt.w;
        coord += objB * (ex * ex + ey * ey + ez * ez + ew * ew);

        float pr_b = best1 ? prB.y : prB.x;
        float lr_b = best1 ? lrB.y : lrB.x;
        float dpo = pr_b - mx, dio = mx - lr_b;
        pobj += objB * dpo * dpo;
        iouL += objB * dio * dio;
    }

    // ---- wave (64-lane) reduction ----
    #pragma unroll
    for (int off = 32; off > 0; off >>= 1) {
        coord += __shfl_down(coord, off);
        cls   += __shfl_down(cls,   off);
        pobj  += __shfl_down(pobj,  off);
        nobj  += __shfl_down(nobj,  off);
        iouL  += __shfl_down(iouL,  off);
    }

    // ---- block reduction (4 waves) ----
    __shared__ float part[4][5];
    int wave = threadIdx.x >> 6;
    int lane = threadIdx.x & 63;
    if (lane == 0) {
        part[wave][0] = coord;
        part[wave][1] = cls;
        part[wave][2] = pobj;
        part[wave][3] = nobj;
        part[wave][4] = iouL;
    }
    __syncthreads();
    if (threadIdx.x == 0) {
        float* w = ws + (size_t)blockIdx.x * 8;
        w[0] = part[0][0] + part[1][0] + part[2][0] + part[3][0];
        w[1] = part[0][1] + part[1][1] + part[2][1] + part[3][1];
        w[2] = part[0][2] + part[1][2] + part[2][2] + part[3][2];
        w[3] = part[0][3] + part[1][3] + part[2][3] + part[3][3];
        w[4] = part[0][4] + part[1][4] + part[2][4] + part[3][4];
    }
}

__global__ __launch_bounds__(TPB) void yolo_loss_finish(
    const float* __restrict__ ws,   // [BLOCKS][8]
    float* __restrict__ out)        // [5]
{
    float s0 = 0.0f, s1 = 0.0f, s2 = 0.0f, s3 = 0.0f, s4 = 0.0f;
    for (int b = threadIdx.x; b < BLOCKS; b += TPB) {
        const float* w = ws + (size_t)b * 8;
        s0 += w[0]; s1 += w[1]; s2 += w[2]; s3 += w[3]; s4 += w[4];
    }
    #pragma unroll
    for (int off = 32; off > 0; off >>= 1) {
        s0 += __shfl_down(s0, off);
        s1 += __shfl_down(s1, off);
        s2 += __shfl_down(s2, off);
        s3 += __shfl_down(s3, off);
        s4 += __shfl_down(s4, off);
    }
    __shared__ float part[4][5];
    int wave = threadIdx.x >> 6;
    int lane = threadIdx.x & 63;
    if (lane == 0) {
        part[wave][0] = s0; part[wave][1] = s1; part[wave][2] = s2;
        part[wave][3] = s3; part[wave][4] = s4;
    }
    __syncthreads();
    if (threadIdx.x == 0) {
        float t0 = part[0][0] + part[1][0] + part[2][0] + part[3][0];
        float t1 = part[0][1] + part[1][1] + part[2][1] + part[3][1];
        float t2 = part[0][2] + part[1][2] + part[2][2] + part[3][2];
        float t3 = part[0][3] + part[1][3] + part[2][3] + part[3][3];
        float t4 = part[0][4] + part[1][4] + part[2][4] + part[3][4];
        out[0] = L_COORD * INV_BS * t0;
        out[1] = INV_BS * t1;
        out[2] = INV_BS * t2;
        out[3] = L_NOOBJ * INV_BS * t3;
        out[4] = INV_BS * t4;
    }
}

extern "C" void kernel_launch(void* const* d_in, const int* in_sizes, int n_in,
                              void* d_out, int out_size, void* d_ws, size_t ws_size,
                              hipStream_t stream) {
    const float* pred_cls   = (const float*)d_in[0];
    const float* pred_resp  = (const float*)d_in[1];
    const float* pred_bb    = (const float*)d_in[2];
    const float* label_cls  = (const float*)d_in[3];
    const float* label_resp = (const float*)d_in[4];
    const float* label_bb   = (const float*)d_in[5];
    float* ws  = (float*)d_ws;          // BLOCKS*8 floats = 50 KB
    float* out = (float*)d_out;

    yolo_loss_main<<<BLOCKS, TPB, 0, stream>>>(
        pred_cls, pred_resp, pred_bb, label_cls, label_resp, label_bb, ws);
    yolo_loss_finish<<<1, TPB, 0, stream>>>(ws, out);
}

// Round 13
// 195.027 us; speedup vs baseline: 1.0599x; 1.0148x over previous
//
#include <hip/hip_runtime.h>

// YOLOv1 loss on MI355X — round 12 kernel (resubmit; R12 bench failed on GPU
// acquisition): persistent-wave grid-stride streaming.
// Evidence recap: R10 replay with ~zero HBM (all L3) ran at the SAME 73us as
// the 98MB-HBM pass => limiter is the CU<->L2/L3 request path, not HBM.
// Occupancy/MLP/coalescing all null; dur tracks requested bytes at ~2.6GB/ms
// marginal. m13's 6.3TB/s copy uses persistent grid-stride loops — the one
// structure never tried here (all prior kernels were one-shot: load quota,
// stall one full latency, die => issue/drain bubbles, no loop pipelining).
// R12: R11's verified arithmetic + byte-saving address-collapse, recast as
// two grid-stride phases over 2048 blocks. If this nulls (>=62us) =>
// platform floor => ROOFLINE.

constexpr int NCELL  = 4096 * 14 * 14;     // 802816
constexpr int TPB    = 256;
constexpr int BLOCKS = 2048;               // 8 blocks/CU, persistent
constexpr int NT     = BLOCKS * TPB;       // 524288 threads
constexpr int N4CLS  = NCELL * 5;          // 4,014,080 float4-pairs
constexpr int NBOX   = NCELL * 2;          // 1,605,632 boxes

constexpr float INV_BS  = 1.0f / 4096.0f;
constexpr float L_COORD = 5.0f;
constexpr float L_NOOBJ = 0.5f;

__device__ __forceinline__ float iou_corners(float4 t, float4 p) {
    float thx = 0.5f * t.z * t.z;
    float thy = 0.5f * t.w * t.w;
    float t_l = t.x - thx, t_t = t.y - thy;
    float t_r = t.x + thx, t_b = t.y + thy;
    float phx = 0.5f * p.z * p.z;
    float phy = 0.5f * p.w * p.w;
    float p_l = p.x - phx, p_t = p.y - phy;
    float p_r = p.x + phx, p_b = p.y + phy;
    float ltx = fmaxf(t_l, p_l), lty = fmaxf(t_t, p_t);
    float rbx = fminf(t_r, p_r), rby = fminf(t_b, p_b);
    float wx = fmaxf(rbx - ltx, 0.0f), wy = fmaxf(rby - lty, 0.0f);
    float inter = wx * wy;
    float a1 = (t_r - t_l) * (t_b - t_t);
    float a2 = (p_r - p_l) * (p_b - p_t);
    return inter / (a1 + a2 - inter);
}

__global__ __launch_bounds__(TPB) void yolo_loss_main(
    const float* __restrict__ pred_cls,    // [NCELL*20]
    const float* __restrict__ pred_resp,   // [NCELL*2]
    const float* __restrict__ pred_bb,     // [NCELL*8]
    const float* __restrict__ label_cls,   // [NCELL*20]
    const float* __restrict__ label_resp,  // [NCELL*2]
    const float* __restrict__ label_bb,    // [NCELL*8]
    float* __restrict__ ws)                // [BLOCKS][8] partials
{
    const int gtid = blockIdx.x * TPB + threadIdx.x;

    const float4* pc4 = reinterpret_cast<const float4*>(pred_cls);
    const float4* lc4 = reinterpret_cast<const float4*>(label_cls);
    const float4* pb4 = reinterpret_cast<const float4*>(pred_bb);
    const float4* tb4 = reinterpret_cast<const float4*>(label_bb);

    float coord = 0.0f, cls = 0.0f, pobj = 0.0f, nobj = 0.0f, iouL = 0.0f;

    // ---------- Phase 1: boxes, grid-stride (thread = one box) ----------
    // Box pairs (2k,2k+1) land on adjacent lanes (NT and wave bases even),
    // so __shfl_xor(.,1) gives the partner; pairs share the obj bit (tiled
    // label_response), so a noobj pair's collapsed-address garbage is fully
    // masked. NBOX even => pairs never split across the ragged tail.
    #pragma unroll 2
    for (int bi = gtid; bi < NBOX; bi += NT) {
        float lrv = label_resp[bi];
        float prv = pred_resp[bi];
        bool  objb = lrv > 0.0f;
        int   be   = objb ? bi : 0;          // address-collapse: L1-hot line

        float4 p = pb4[be];
        float4 t = tb4[be];

        float iou   = iou_corners(t, p);
        float iou_o = __shfl_xor(iou, 1);
        bool  is_b1 = (bi & 1);
        bool  win   = is_b1 ? (iou > iou_o) : (iou >= iou_o);  // argmax: first max
        float mx    = fmaxf(iou, iou_o);

        float o  = objb ? 1.0f : 0.0f;
        float dr = prv - lrv;
        nobj += (1.0f - o) * dr * dr;        // summed over both boxes

        float wm = (win ? 1.0f : 0.0f) * o;
        float ex = p.x - t.x, ey = p.y - t.y, ez = p.z - t.z, ew = p.w - t.w;
        coord += wm * (ex * ex + ey * ey + ez * ez + ew * ew);
        float dpo = prv - mx;
        float dio = mx - lrv;
        pobj += wm * dpo * dpo;
        iouL += wm * dio * dio;
    }

    // ---------- Phase 2: classification, grid-stride float4 stream ----------
    #pragma unroll 2
    for (int i4 = gtid; i4 < N4CLS; i4 += NT) {
        unsigned cell = (unsigned)i4 / 5u;                 // magic-mul div
        float m = label_resp[(size_t)cell * 2];            // ~1-2 lines/wave
        bool  objc = m > 0.0f;
        int   ie   = objc ? i4 : 0;                        // collapse to line 0

        float4 a = pc4[ie];
        float4 b = lc4[ie];
        float dx = a.x - b.x, dy = a.y - b.y, dz = a.z - b.z, dw = a.w - b.w;
        float s = dx * dx + dy * dy + dz * dz + dw * dw;
        cls += (objc ? 1.0f : 0.0f) * s;
    }

    // ---- wave (64-lane) reduction ----
    #pragma unroll
    for (int off = 32; off > 0; off >>= 1) {
        coord += __shfl_down(coord, off);
        cls   += __shfl_down(cls,   off);
        pobj  += __shfl_down(pobj,  off);
        nobj  += __shfl_down(nobj,  off);
        iouL  += __shfl_down(iouL,  off);
    }

    // ---- block reduction (4 waves) ----
    __shared__ float part[4][5];
    int wave = threadIdx.x >> 6;
    int lane = threadIdx.x & 63;
    if (lane == 0) {
        part[wave][0] = coord;
        part[wave][1] = cls;
        part[wave][2] = pobj;
        part[wave][3] = nobj;
        part[wave][4] = iouL;
    }
    __syncthreads();
    if (threadIdx.x == 0) {
        float* w = ws + (size_t)blockIdx.x * 8;
        w[0] = part[0][0] + part[1][0] + part[2][0] + part[3][0];
        w[1] = part[0][1] + part[1][1] + part[2][1] + part[3][1];
        w[2] = part[0][2] + part[1][2] + part[2][2] + part[3][2];
        w[3] = part[0][3] + part[1][3] + part[2][3] + part[3][3];
        w[4] = part[0][4] + part[1][4] + part[2][4] + part[3][4];
    }
}

__global__ __launch_bounds__(TPB) void yolo_loss_finish(
    const float* __restrict__ ws,   // [BLOCKS][8]
    float* __restrict__ out)        // [5]
{
    float s0 = 0.0f, s1 = 0.0f, s2 = 0.0f, s3 = 0.0f, s4 = 0.0f;
    for (int b = threadIdx.x; b < BLOCKS; b += TPB) {
        const float* w = ws + (size_t)b * 8;
        s0 += w[0]; s1 += w[1]; s2 += w[2]; s3 += w[3]; s4 += w[4];
    }
    #pragma unroll
    for (int off = 32; off > 0; off >>= 1) {
        s0 += __shfl_down(s0, off);
        s1 += __shfl_down(s1, off);
        s2 += __shfl_down(s2, off);
        s3 += __shfl_down(s3, off);
        s4 += __shfl_down(s4, off);
    }
    __shared__ float part[4][5];
    int wave = threadIdx.x >> 6;
    int lane = threadIdx.x & 63;
    if (lane == 0) {
        part[wave][0] = s0; part[wave][1] = s1; part[wave][2] = s2;
        part[wave][3] = s3; part[wave][4] = s4;
    }
    __syncthreads();
    if (threadIdx.x == 0) {
        float t0 = part[0][0] + part[1][0] + part[2][0] + part[3][0];
        float t1 = part[0][1] + part[1][1] + part[2][1] + part[3][1];
        float t2 = part[0][2] + part[1][2] + part[2][2] + part[3][2];
        float t3 = part[0][3] + part[1][3] + part[2][3] + part[3][3];
        float t4 = part[0][4] + part[1][4] + part[2][4] + part[3][4];
        out[0] = L_COORD * INV_BS * t0;
        out[1] = INV_BS * t1;
        out[2] = INV_BS * t2;
        out[3] = L_NOOBJ * INV_BS * t3;
        out[4] = INV_BS * t4;
    }
}

extern "C" void kernel_launch(void* const* d_in, const int* in_sizes, int n_in,
                              void* d_out, int out_size, void* d_ws, size_t ws_size,
                              hipStream_t stream) {
    const float* pred_cls   = (const float*)d_in[0];
    const float* pred_resp  = (const float*)d_in[1];
    const float* pred_bb    = (const float*)d_in[2];
    const float* label_cls  = (const float*)d_in[3];
    const float* label_resp = (const float*)d_in[4];
    const float* label_bb   = (const float*)d_in[5];
    float* ws  = (float*)d_ws;          // BLOCKS*8 floats = 64 KB
    float* out = (float*)d_out;

    yolo_loss_main<<<BLOCKS, TPB, 0, stream>>>(
        pred_cls, pred_resp, pred_bb, label_cls, label_resp, label_bb, ws);
    yolo_loss_finish<<<1, TPB, 0, stream>>>(ws, out);
}